// Round 4
// baseline (2643.010 us; speedup 1.0000x reference)
//
#include <hip/hip_runtime.h>
#include <hip/hip_bf16.h>

#define D      64
#define HID    36
#define IN_DIM 192
#define NPB    64        // nodes per bucket (node >> 6)
#define MAXNB  2048      // max buckets supported (n_nodes <= 131072)
#define CHUNK  16384     // endpoint records per partition block

// ---------------------------------------------------------------------------
// FALLBACK: R0 atomic-scatter path kernels
// ---------------------------------------------------------------------------
__global__ void zero_ws_kernel(float4* __restrict__ p, long n4) {
    long i = (long)blockIdx.x * blockDim.x + threadIdx.x;
    long stride = (long)gridDim.x * blockDim.x;
    float4 z = make_float4(0.f, 0.f, 0.f, 0.f);
    for (; i < n4; i += stride) p[i] = z;
}

__global__ __launch_bounds__(256) void scatter_kernel(
    const float* __restrict__ edges,
    const int* __restrict__ senders,
    const int* __restrict__ receivers,
    float* __restrict__ sent,
    float* __restrict__ recv,
    long total)
{
    long i = (long)blockIdx.x * blockDim.x + threadIdx.x;
    if (i >= total) return;
    long e = i >> 6;
    int  d = (int)(i & 63);
    float v = edges[i];
    unsafeAtomicAdd(&sent[(long)senders[e] * D + d], v);
    unsafeAtomicAdd(&recv[(long)receivers[e] * D + d], v);
}

// ---------------------------------------------------------------------------
// K_a: per-block bucket histogram.
// Endpoint record i in [0, 2E): i<E -> (edge=i, dir=0, node=senders[i])
//                               else (edge=i-E, dir=1, node=receivers[i-E])
// ---------------------------------------------------------------------------
__global__ __launch_bounds__(256) void count_kernel(
    const int* __restrict__ senders,
    const int* __restrict__ receivers,
    int* __restrict__ counts,          // [nblocks][NB]
    int NB, long E, long total_items)
{
    __shared__ int hist[MAXNB];
    for (int b = threadIdx.x; b < NB; b += 256) hist[b] = 0;
    __syncthreads();

    long start = (long)blockIdx.x * CHUNK;
    long end = start + CHUNK; if (end > total_items) end = total_items;
    for (long i = start + threadIdx.x; i < end; i += 256) {
        int node = (i < E) ? senders[i] : receivers[i - E];
        atomicAdd(&hist[node >> 6], 1);
    }
    __syncthreads();
    int* row = counts + (long)blockIdx.x * NB;
    for (int b = threadIdx.x; b < NB; b += 256) row[b] = hist[b];
}

// ---------------------------------------------------------------------------
// K_b1: per-bucket column exclusive scan over blocks; tot[b] = column sum.
// one thread per bucket; loads coalesced across threads.
// ---------------------------------------------------------------------------
__global__ __launch_bounds__(256) void colscan_kernel(
    int* __restrict__ counts, int* __restrict__ tot, int NB, int nblocks)
{
    int b = blockIdx.x * 256 + threadIdx.x;
    if (b >= NB) return;
    int run = 0;
#pragma unroll 4
    for (int blk = 0; blk < nblocks; ++blk) {
        long idx = (long)blk * NB + b;
        int c = counts[idx];
        counts[idx] = run;
        run += c;
    }
    tot[b] = run;
}

// ---------------------------------------------------------------------------
// K_b2: exclusive scan of tot[NB] -> base[NB].  Single block, 1024 threads,
// double-buffered Hillis-Steele over MAXNB=2048 slots.
// ---------------------------------------------------------------------------
__global__ __launch_bounds__(1024) void basescan_kernel(
    const int* __restrict__ tot, int* __restrict__ base, int NB)
{
    __shared__ int sA[2][MAXNB];
    int t = threadIdx.x;
    sA[0][t]        = (t < NB) ? tot[t] : 0;
    sA[0][t + 1024] = (t + 1024 < NB) ? tot[t + 1024] : 0;
    __syncthreads();
    int src = 0;
    for (int off = 1; off < MAXNB; off <<= 1) {
        int dst = src ^ 1;
        int i0 = t, i1 = t + 1024;
        sA[dst][i0] = sA[src][i0] + ((i0 >= off) ? sA[src][i0 - off] : 0);
        sA[dst][i1] = sA[src][i1] + ((i1 >= off) ? sA[src][i1 - off] : 0);
        src = dst;
        __syncthreads();
    }
    if (t < NB)        base[t]        = (t == 0) ? 0 : sA[src][t - 1];
    if (t + 1024 < NB) base[t + 1024] = sA[src][t + 1023];
}

// ---------------------------------------------------------------------------
// K_c: place records. cursor[b] = base[b] + counts[myblk][b]; LDS returning
// atomics only (contention ~10-way within block). rec = edge<<7 | dir<<6 | nl.
// ---------------------------------------------------------------------------
__global__ __launch_bounds__(256) void scatter_ids_kernel(
    const int* __restrict__ senders,
    const int* __restrict__ receivers,
    const int* __restrict__ counts,
    const int* __restrict__ base,
    unsigned* __restrict__ pool,
    int NB, long E, long total_items)
{
    __shared__ int cursor[MAXNB];
    const int* row = counts + (long)blockIdx.x * NB;
    for (int b = threadIdx.x; b < NB; b += 256) cursor[b] = row[b] + base[b];
    __syncthreads();

    long start = (long)blockIdx.x * CHUNK;
    long end = start + CHUNK; if (end > total_items) end = total_items;
    for (long i = start + threadIdx.x; i < end; i += 256) {
        int dir, node; long edge;
        if (i < E) { dir = 0; edge = i;     node = senders[i]; }
        else       { dir = 1; edge = i - E; node = receivers[i - E]; }
        int b = node >> 6;
        int pos = atomicAdd(&cursor[b], 1);
        pool[pos] = ((unsigned)edge << 7) | ((unsigned)dir << 6) | (unsigned)(node & 63);
    }
}

// ---------------------------------------------------------------------------
// K_d: one block per bucket.  LDS accum [64 nodes][sent 64 | recv 64] f32.
// Wave reads 64 records coalesced, broadcasts via shfl; per record one 256B
// coalesced edge-row read + one ds_add_f32 per lane (2-way bank alias = free).
// ---------------------------------------------------------------------------
__global__ __launch_bounds__(256) void accum_kernel(
    const float* __restrict__ edges,
    const unsigned* __restrict__ pool,
    const int* __restrict__ base,
    const int* __restrict__ tot,
    float* __restrict__ sent,
    float* __restrict__ recv,
    int n_nodes)
{
    __shared__ float accum[NPB][2 * D];    // 32 KB
    int tid = threadIdx.x;
    for (int i = tid; i < NPB * 2 * D; i += 256) ((float*)accum)[i] = 0.f;
    __syncthreads();

    int b = blockIdx.x;
    int start = base[b];
    int end = start + tot[b];
    int wave = tid >> 6, lane = tid & 63;

    for (int c = start + wave * 64; c < end; c += 256) {
        int nb = end - c; if (nb > 64) nb = 64;
        unsigned rec = (c + lane < end) ? pool[c + lane] : 0u;
        int j = 0;
        for (; j + 4 <= nb; j += 4) {
            unsigned r0 = __shfl(rec, j,     64);
            unsigned r1 = __shfl(rec, j + 1, 64);
            unsigned r2 = __shfl(rec, j + 2, 64);
            unsigned r3 = __shfl(rec, j + 3, 64);
            float v0 = edges[(long)(r0 >> 7) * D + lane];
            float v1 = edges[(long)(r1 >> 7) * D + lane];
            float v2 = edges[(long)(r2 >> 7) * D + lane];
            float v3 = edges[(long)(r3 >> 7) * D + lane];
            atomicAdd(&accum[r0 & 63][((r0 >> 6) & 1) * D + lane], v0);
            atomicAdd(&accum[r1 & 63][((r1 >> 6) & 1) * D + lane], v1);
            atomicAdd(&accum[r2 & 63][((r2 >> 6) & 1) * D + lane], v2);
            atomicAdd(&accum[r3 & 63][((r3 >> 6) & 1) * D + lane], v3);
        }
        for (; j < nb; ++j) {
            unsigned r = __shfl(rec, j, 64);
            float v = edges[(long)(r >> 7) * D + lane];
            atomicAdd(&accum[r & 63][((r >> 6) & 1) * D + lane], v);
        }
    }
    __syncthreads();

    int node0 = b * NPB;
    for (int i = tid; i < NPB * D; i += 256) {
        int nl = i >> 6, k = i & 63;
        int node = node0 + nl;
        if (node < n_nodes) {
            sent[(long)node * D + k] = accum[nl][k];
            recv[(long)node * D + k] = accum[nl][D + k];
        }
    }
}

// ---------------------------------------------------------------------------
// per-node MLP (R0 version, exact f32)
// ---------------------------------------------------------------------------
__global__ __launch_bounds__(256) void mlp_kernel(
    const float* __restrict__ nodes,
    const float* __restrict__ sent,
    const float* __restrict__ recv,
    const float* __restrict__ W1,
    const float* __restrict__ b1,
    const float* __restrict__ W2,
    const float* __restrict__ b2,
    float* __restrict__ out,
    int n)
{
    __shared__ float sW1[IN_DIM * HID];
    __shared__ float sb1[HID];
    __shared__ float sW2[HID * 2];
    __shared__ float sb2[2];

    for (int t = threadIdx.x; t < IN_DIM * HID; t += blockDim.x) sW1[t] = W1[t];
    if (threadIdx.x < HID)     sb1[threadIdx.x] = b1[threadIdx.x];
    if (threadIdx.x < HID * 2) sW2[threadIdx.x] = W2[threadIdx.x];
    if (threadIdx.x < 2)       sb2[threadIdx.x] = b2[threadIdx.x];
    __syncthreads();

    int node = blockIdx.x * blockDim.x + threadIdx.x;
    if (node >= n) return;

    float acc[HID];
#pragma unroll
    for (int j = 0; j < HID; ++j) acc[j] = sb1[j];

#pragma unroll
    for (int part = 0; part < 3; ++part) {
        const float* f = (part == 0 ? nodes : (part == 1 ? sent : recv)) + (long)node * D;
        const float* w = sW1 + part * D * HID;
        for (int k = 0; k < D; k += 4) {
            float4 fv = *reinterpret_cast<const float4*>(f + k);
#pragma unroll
            for (int j = 0; j < HID; ++j) {
                acc[j] += fv.x * w[(k + 0) * HID + j];
                acc[j] += fv.y * w[(k + 1) * HID + j];
                acc[j] += fv.z * w[(k + 2) * HID + j];
                acc[j] += fv.w * w[(k + 3) * HID + j];
            }
        }
    }

    float o0 = sb2[0], o1 = sb2[1];
#pragma unroll
    for (int j = 0; j < HID; ++j) {
        float h = fmaxf(acc[j], 0.f);
        o0 += h * sW2[j * 2 + 0];
        o1 += h * sW2[j * 2 + 1];
    }
    reinterpret_cast<float2*>(out)[node] = make_float2(o0, o1);
}

// ---------------------------------------------------------------------------
extern "C" void kernel_launch(void* const* d_in, const int* in_sizes, int n_in,
                              void* d_out, int out_size, void* d_ws, size_t ws_size,
                              hipStream_t stream) {
    const float* nodes     = (const float*)d_in[0];
    const float* edges     = (const float*)d_in[1];
    const int*   senders   = (const int*)d_in[2];
    const int*   receivers = (const int*)d_in[3];
    const float* W1        = (const float*)d_in[4];
    const float* b1        = (const float*)d_in[5];
    const float* W2        = (const float*)d_in[6];
    const float* b2        = (const float*)d_in[7];
    float* out = (float*)d_out;

    const int  n_nodes = in_sizes[0] / D;      // 100,000
    const long E       = in_sizes[2];          // 3,200,000
    const long total_items = 2 * E;            // 6.4M endpoint records

    const int NB      = (n_nodes + NPB - 1) / NPB;            // 1563
    const int nblocks = (int)((total_items + CHUNK - 1) / CHUNK); // 391

    // ws layout: [sent 25.6MB | recv 25.6MB | pool 25.6MB | tot 8KB | base 8KB]
    // counts[nblocks][NB] aliases the sent region (disjoint lifetime).
    const size_t sz_sent = (size_t)n_nodes * D * sizeof(float);
    const size_t sz_pool = (size_t)total_items * sizeof(unsigned);
    const size_t sz_nb   = (size_t)MAXNB * sizeof(int);
    const size_t need    = 2 * sz_sent + sz_pool + 2 * sz_nb;
    const size_t sz_counts = (size_t)nblocks * NB * sizeof(int);

    char* wp = (char*)d_ws;
    float*    sent = (float*)wp;            wp += sz_sent;
    float*    recv = (float*)wp;            wp += sz_sent;
    unsigned* pool = (unsigned*)wp;         wp += sz_pool;
    int*      tot  = (int*)wp;              wp += sz_nb;
    int*      base = (int*)wp;
    int*      counts = (int*)sent;          // aliased, lifetime ends at K_c

    if (ws_size < need || NB > MAXNB || sz_counts > sz_sent) {
        // FALLBACK: R0 atomic-scatter path
        long n4 = (long)n_nodes * D * 2 / 4;
        zero_ws_kernel<<<2048, 256, 0, stream>>>((float4*)d_ws, n4);
        long total = E * D;
        scatter_kernel<<<(int)((total + 255) / 256), 256, 0, stream>>>(
            edges, senders, receivers, sent, recv, total);
        mlp_kernel<<<(n_nodes + 255) / 256, 256, 0, stream>>>(
            nodes, sent, recv, W1, b1, W2, b2, out, n_nodes);
        return;
    }

    count_kernel<<<nblocks, 256, 0, stream>>>(senders, receivers, counts,
                                              NB, E, total_items);
    colscan_kernel<<<(NB + 255) / 256, 256, 0, stream>>>(counts, tot, NB, nblocks);
    basescan_kernel<<<1, 1024, 0, stream>>>(tot, base, NB);
    scatter_ids_kernel<<<nblocks, 256, 0, stream>>>(senders, receivers, counts,
                                                    base, pool, NB, E, total_items);
    accum_kernel<<<NB, 256, 0, stream>>>(edges, pool, base, tot,
                                         sent, recv, n_nodes);
    mlp_kernel<<<(n_nodes + 255) / 256, 256, 0, stream>>>(
        nodes, sent, recv, W1, b1, W2, b2, out, n_nodes);
}